// Round 4
// baseline (227.991 us; speedup 1.0000x reference)
//
#include <hip/hip_runtime.h>
#include <cstddef>
#include <cstdint>

// z: (8, 256, 16,16,16) fp32; embedding: (1024, 256) fp32
#define CDIM 256
#define SPAT 4096
#define KCODE 1024

#define LOSS_OFF 8388608
#define PERP_OFF 8388609
#define IDX_OFF  8388610

typedef __bf16 bf16x8 __attribute__((ext_vector_type(8)));
typedef float floatx16 __attribute__((ext_vector_type(16)));
typedef unsigned short ushort8 __attribute__((ext_vector_type(8)));

__device__ __forceinline__ unsigned short f2bf_rne(float f) {
    union { float f; uint32_t u; } c; c.f = f;
    uint32_t u = c.u;
    return (unsigned short)((u + 0x7fffu + ((u >> 16) & 1u)) >> 16);
}
__device__ __forceinline__ float bf2f(unsigned short h) {
    union { float f; uint32_t u; } c; c.u = ((uint32_t)h) << 16;
    return c.f;
}

// async global->LDS, 16B per lane; lds dest = uniform base + lane*16 (HW adds)
__device__ __forceinline__ void dma16(const void* g, void* l) {
    __builtin_amdgcn_global_load_lds(
        (const __attribute__((address_space(1))) void*)g,
        (__attribute__((address_space(3))) void*)l, 16, 0, 0);
}

// ---------------------------------------------------------------------------
// Prep: split embedding into bf16 hi/lo in the bank-swizzled stage layout:
//   ushort index = stage*8192 + ks*256 + phys*8 + (c&7)
//   phys = kb ^ (ks & 7),  kb = c>>3 (0..31), ks = code&31, stage = code>>5
// Also enorm (exact R1 reduction order), zero counts/losssum/flags, pbm=~0.
// ---------------------------------------------------------------------------
__global__ __launch_bounds__(256) void vq_prep(const float* __restrict__ emb,
                                               unsigned short* __restrict__ ehsw,
                                               unsigned short* __restrict__ elsw,
                                               float* __restrict__ enorm,
                                               float* __restrict__ counts,
                                               float* __restrict__ losssum,
                                               unsigned long long* __restrict__ pbm,
                                               unsigned int* __restrict__ flags) {
    int tid = threadIdx.x;
    if (blockIdx.x == 0) {
        for (int i = tid; i < KCODE; i += 256) counts[i] = 0.0f;
        if (tid == 0) losssum[0] = 0.0f;
    }
    if (blockIdx.x == 1) flags[tid] = 0u;   // 256 pos-tile flags
    // per-position packed (dist,code) min-key init: +NaN bits > any real key
    if (tid < 128) pbm[blockIdx.x * 128 + tid] = 0xFFFFFFFFFFFFFFFFull;

    int w = tid >> 6, lane = tid & 63;
    int k = blockIdx.x * 4 + w;
    const float* row = emb + (size_t)k * CDIM;
    float s = 0.0f;
#pragma unroll
    for (int i = 0; i < 4; ++i) {
        float v = row[lane + 64 * i];
        s = fmaf(v, v, s);
    }
#pragma unroll
    for (int m = 32; m > 0; m >>= 1) s += __shfl_xor(s, m, 64);
    if (lane == 0) enorm[k] = s;

    float4 v4 = *(const float4*)(row + lane * 4);
    unsigned short h0 = f2bf_rne(v4.x), h1 = f2bf_rne(v4.y),
                   h2 = f2bf_rne(v4.z), h3 = f2bf_rne(v4.w);
    ushort4 hv = make_ushort4(h0, h1, h2, h3);
    ushort4 lv = make_ushort4(f2bf_rne(v4.x - bf2f(h0)), f2bf_rne(v4.y - bf2f(h1)),
                              f2bf_rne(v4.z - bf2f(h2)), f2bf_rne(v4.w - bf2f(h3)));
    int kb = lane >> 1, cj = (lane & 1) * 4;
    int st = k >> 5, ks = k & 31;
    int phys = kb ^ (ks & 7);
    size_t dst = (size_t)st * 8192 + ks * 256 + phys * 8 + cj;
    *(ushort4*)(ehsw + dst) = hv;
    *(ushort4*)(elsw + dst) = lv;
}

// ---------------------------------------------------------------------------
// Dist + fused gather: 512 blocks x 256 threads (4 waves), 2 blocks/CU.
// Block = (pos tile, code half kh). Stage loop identical to R3 (numerics
// untouched). After the packed-u64 atomicMin merge, the LAST-arriving block
// of each pos tile (flags handshake, release/acquire via __threadfence)
// performs the gather/loss tail in-kernel:
//  - reads merged keys with agent-scope atomic loads (XCD-coherent),
//  - reuses the 68KB LDS as 64 x 1040B row slots, two rounds of 64 rows
//    split by col4 so each thread runs its COMPLETE original c-chain in one
//    round -> per-thread fmaf chains / wave reduce / 4 loss partials per
//    tile are bit-identical to R1/R2.
// This kills the separate gather kernel (~50us: launch + cold z re-read +
// pbm round-trip) and overlaps gather work with other CUs' stage loops.
// ---------------------------------------------------------------------------
__global__ __launch_bounds__(256, 2) void vq_dist(const float* __restrict__ z,
                                                  const float* __restrict__ emb,
                                                  const unsigned short* __restrict__ ehsw,
                                                  const unsigned short* __restrict__ elsw,
                                                  const float* __restrict__ enorm,
                                                  unsigned long long* __restrict__ pbm,
                                                  unsigned int* __restrict__ flags,
                                                  float* __restrict__ counts,
                                                  float* __restrict__ losssum,
                                                  float* __restrict__ out) {
    __shared__ __align__(16) unsigned char lds[65536 + 2048 + 512];
    float* zhalf = (float*)lds;                 // phase1 overlay on both dbufs
    float* ens_s = (float*)(lds + 65536);       // 512 f (this kh's enorm)
    float* zzs   = (float*)(lds + 67584);       // 128 f
    __shared__ int last_s;

    const int tid = threadIdx.x;
    const int w = tid >> 6;            // wave id 0..3
    const int lane = tid & 63;
    const int m_ = lane & 31;
    const int g = lane >> 5;
    const int bid = blockIdx.x;
    const int pos = bid >> 1;
    const int kh = bid & 1;
    const int ch = w & 1;              // 32-col offset within the 64-col half
    const int hlf = w >> 1;            // which 64-col half this wave extracts
    const int n0 = pos * 128;
    const int b = n0 >> 12;
    const int sp0 = n0 & 4095;
    const float* zb = z + (size_t)b * CDIM * SPAT + sp0;
    const int stg0 = (bid >> 4) & 15;  // stage stagger (harmless, keep)

    ushort8 zh[16], zl[16];

    // ---- phase 1: two 64-col halves ----
    for (int h = 0; h < 2; ++h) {
        for (int i = tid; i < CDIM * 16; i += 256) {
            int c = i >> 4, seg = i & 15;
            *(float4*)&zhalf[c * 64 + seg * 4] =
                *(const float4*)(zb + (size_t)c * SPAT + h * 64 + seg * 4);
        }
        __syncthreads();
        if (hlf == h) {
#pragma unroll
            for (int kc = 0; kc < 16; ++kc) {
#pragma unroll
                for (int j = 0; j < 8; ++j) {
                    float v = zhalf[(kc * 16 + g * 8 + j) * 64 + ch * 32 + m_];
                    unsigned short hb = f2bf_rne(v);
                    unsigned short lb = f2bf_rne(v - bf2f(hb));
                    zh[kc][j] = hb; zl[kc][j] = lb;
                }
            }
        } else if (w == (h == 0 ? 2 : 0)) {
            // zz per column (R1-exact sequential fmaf order)
            float s = 0.0f;
            for (int c = 0; c < CDIM; ++c) {
                float v = zhalf[c * 64 + lane];
                s = fmaf(v, v, s);
            }
            zzs[h * 64 + lane] = s;
        } else if (h == 0 && w == 3) {
            for (int i = lane; i < 512; i += 64) ens_s[i] = enorm[kh * 512 + i];
        }
        __syncthreads();
    }

    const float zzv = zzs[w * 32 + m_];

    float bs = 3.4e38f;
    int bi_ = 0;

    // wave's DMA role: bufid = w>>1 (0:eh, 1:el), hf = w&1 (8 KB half)
    const int bufid = w >> 1;
    const int hf = w & 1;
    const char* gsrc = (const char*)(bufid ? elsw : ehsw);
    const int gs0 = kh * 16;           // global stage base for this code half

    // ---- stage-0 DMA prologue (staggered stage stg0 -> buf0) ----
    {
        const char* gp = gsrc + ((size_t)(gs0 + stg0) << 14) + (hf << 13) + (lane << 4);
        char* lp = (char*)lds + ((size_t)bufid << 14) + (hf << 13);
#pragma unroll
        for (int j = 0; j < 8; ++j) dma16(gp + j * 1024, lp + j * 1024);
    }

    // ---- main loop: 16 stages, double-buffered (2x32 KB) ----
    for (int s = 0; s < 16; ++s) {
        __syncthreads();   // drains DMA(s); all waves done with buf[(s+1)&1]
        if (s < 15) {
            const int se_n = (s + 1 + stg0) & 15;
            const char* gp = gsrc + ((size_t)(gs0 + se_n) << 14) + (hf << 13) + (lane << 4);
            char* lp = (char*)lds + (((size_t)(s + 1) & 1) << 15) +
                       ((size_t)bufid << 14) + (hf << 13);
#pragma unroll
            for (int j = 0; j < 8; ++j) dma16(gp + j * 1024, lp + j * 1024);
            __builtin_amdgcn_sched_barrier(0);   // keep DMA issue above compute
        }
        const char* EHb = (const char*)lds + (((size_t)s & 1) << 15);
        const char* ELb = EHb + 16384;

        floatx16 a = {0.0f, 0.0f, 0.0f, 0.0f, 0.0f, 0.0f, 0.0f, 0.0f,
                      0.0f, 0.0f, 0.0f, 0.0f, 0.0f, 0.0f, 0.0f, 0.0f};
#pragma unroll
        for (int kc = 0; kc < 16; ++kc) {
            int kb0 = kc * 2 + g;
            int off = m_ * 512 + ((kb0 ^ (m_ & 7)) << 4);
            bf16x8 aeh = *(const bf16x8*)(EHb + off);
            bf16x8 ael = *(const bf16x8*)(ELb + off);
            bf16x8 bh = __builtin_bit_cast(bf16x8, zh[kc]);
            bf16x8 bl = __builtin_bit_cast(bf16x8, zl[kc]);
            a = __builtin_amdgcn_mfma_f32_32x32x16_bf16(aeh, bh, a, 0, 0, 0);
            a = __builtin_amdgcn_mfma_f32_32x32x16_bf16(ael, bh, a, 0, 0, 0);
            a = __builtin_amdgcn_mfma_f32_32x32x16_bf16(aeh, bl, a, 0, 0, 0);
        }

        // epilogue: order-independent lexicographic (d, code) argmin
        const int se = (s + stg0) & 15;
#pragma unroll
        for (int reg = 0; reg < 16; ++reg) {
            int mm = (reg & 3) + 8 * (reg >> 2) + 4 * g;
            int il = se * 32 + mm;
            float en = ens_s[il];
            float d = (zzv + en) - 2.0f * a[reg];
            int code = kh * 512 + il;
            if (d < bs || (d == bs && code < bi_)) { bs = d; bi_ = code; }
        }
    }

    // ---- merge g-halves (disjoint code subsets), tie -> low index ----
    {
        float s2 = __shfl_xor(bs, 32, 64);
        int i2 = __shfl_xor(bi_, 32, 64);
        if (s2 < bs || (s2 == bs && i2 < bi_)) { bs = s2; bi_ = i2; }
    }
    // ---- cross-kh merge via packed atomicMin (exact lexicographic) ----
    if (lane < 32) {
        unsigned long long key =
            ((unsigned long long)__float_as_uint(bs) << 32) | (unsigned int)bi_;
        atomicMin(&pbm[n0 + w * 32 + m_], key);
    }
    __threadfence();        // release: this wave's mins visible device-wide
    __syncthreads();        // all waves past their fences
    if (tid == 0) last_s = (atomicAdd(&flags[pos], 1u) == 1u);
    __syncthreads();
    if (!last_s) return;    // first-arriver exits; exactly one block gathers
    __threadfence();        // acquire: other block's mins now visible

    // ---- gather tail (last-arriver block only) ----
    int* bidxs = (int*)(lds + 67584);       // 128 i (zzs region, dead)
    if (tid < 128) {
        unsigned long long key = __hip_atomic_load(
            &pbm[n0 + tid], __ATOMIC_RELAXED, __HIP_MEMORY_SCOPE_AGENT);
        int ki = (int)(unsigned int)(key & 0xFFFFFFFFull);
        bidxs[tid] = ki;
        out[IDX_OFF + n0 + tid] = (float)ki;
        atomicAdd(&counts[ki], 1.0f);
    }
    __syncthreads();

    // two rounds of 64 rows; slots [0, 66544) stride 1040B; bidxs at 67584.
    // round r serves threads with col4>>4 == r; each active thread runs its
    // COMPLETE original c-chain (bit-identical loss partials).
    float ls = 0.0f;
    float* outz = out + (size_t)b * CDIM * SPAT + sp0;
    const int col4 = tid & 31;
    const int c_0t = tid >> 5;
    const int col4h = col4 & 15;
    for (int round = 0; round < 2; ++round) {
#pragma unroll
        for (int r = 0; r < 16; ++r) {
            int row_local = w * 16 + r;                 // 0..63
            int k = bidxs[round * 64 + row_local];
            int slot = (row_local & 3) * 16 + (row_local >> 2);
            dma16((const char*)emb + ((size_t)k << 10) + (lane << 4),
                  (char*)lds + (size_t)slot * 1040);
        }
        __syncthreads();
        if ((col4 >> 4) == round) {
            const float* e0 = (const float*)((const char*)lds + (size_t)(0 * 16 + col4h) * 1040);
            const float* e1 = (const float*)((const char*)lds + (size_t)(1 * 16 + col4h) * 1040);
            const float* e2 = (const float*)((const char*)lds + (size_t)(2 * 16 + col4h) * 1040);
            const float* e3 = (const float*)((const char*)lds + (size_t)(3 * 16 + col4h) * 1040);
            for (int c = c_0t; c < CDIM; c += 8) {
                float4 zp = *(const float4*)(zb + (size_t)c * SPAT + col4 * 4);
                float d0 = e0[c] - zp.x, d1 = e1[c] - zp.y,
                      d2 = e2[c] - zp.z, d3 = e3[c] - zp.w;
                float4 o;
                o.x = zp.x + d0; o.y = zp.y + d1; o.z = zp.z + d2; o.w = zp.w + d3;
                ls = fmaf(d0, d0, ls); ls = fmaf(d1, d1, ls);
                ls = fmaf(d2, d2, ls); ls = fmaf(d3, d3, ls);
                *(float4*)(outz + (size_t)c * SPAT + col4 * 4) = o;
            }
        }
        __syncthreads();    // all reads done before next round's DMA
    }
#pragma unroll
    for (int m = 32; m > 0; m >>= 1) ls += __shfl_xor(ls, m, 64);
    if (lane == 0) atomicAdd(losssum, ls);
}

// ---------------------------------------------------------------------------
// loss + perplexity
// ---------------------------------------------------------------------------
__global__ __launch_bounds__(256) void vq_finalize(const float* __restrict__ counts,
                                                   const float* __restrict__ losssum,
                                                   float* __restrict__ out) {
    __shared__ float red[256];
    int tid = threadIdx.x;
    float s = 0.0f;
    for (int k = tid; k < KCODE; k += 256) {
        float em = counts[k] * (1.0f / 32768.0f);
        s += em * logf(em + 1e-10f);
    }
    red[tid] = s;
    __syncthreads();
    for (int off = 128; off > 0; off >>= 1) {
        if (tid < off) red[tid] += red[tid + off];
        __syncthreads();
    }
    if (tid == 0) {
        float m = losssum[0] * (1.0f / 8388608.0f);
        out[LOSS_OFF] = m + 0.25f * m;
        out[PERP_OFF] = expf(-red[0]);
    }
}

extern "C" void kernel_launch(void* const* d_in, const int* in_sizes, int n_in,
                              void* d_out, int out_size, void* d_ws, size_t ws_size,
                              hipStream_t stream) {
    const float* z = (const float*)d_in[0];
    const float* emb = (const float*)d_in[1];
    float* out = (float*)d_out;
    // workspace: pbm | ehsw | elsw | enorm | counts | losssum | flags
    unsigned long long* pbm = (unsigned long long*)d_ws;     // 32768 u64 (256 KB)
    unsigned short* ehsw = (unsigned short*)(pbm + 32768);   // 1024*256 ushort
    unsigned short* elsw = ehsw + (size_t)KCODE * CDIM;      // 1024*256 ushort
    float* enorm = (float*)(elsw + (size_t)KCODE * CDIM);    // 1024 f
    float* counts = enorm + KCODE;                           // 1024 f
    float* losssum = counts + KCODE;                         // 1 f
    unsigned int* flags = (unsigned int*)(losssum + 1);      // 256 u32

    vq_prep<<<256, 256, 0, stream>>>(emb, ehsw, elsw, enorm, counts, losssum, pbm, flags);
    vq_dist<<<512, 256, 0, stream>>>(z, emb, ehsw, elsw, enorm, pbm, flags,
                                     counts, losssum, out);
    vq_finalize<<<1, 256, 0, stream>>>(counts, losssum, out);
}

// Round 5
// 197.282 us; speedup vs baseline: 1.1557x; 1.1557x over previous
//
#include <hip/hip_runtime.h>
#include <cstddef>
#include <cstdint>

// z: (8, 256, 16,16,16) fp32; embedding: (1024, 256) fp32
#define CDIM 256
#define SPAT 4096
#define KCODE 1024

#define LOSS_OFF 8388608
#define PERP_OFF 8388609
#define IDX_OFF  8388610

typedef __bf16 bf16x8 __attribute__((ext_vector_type(8)));
typedef float floatx16 __attribute__((ext_vector_type(16)));
typedef unsigned short ushort8 __attribute__((ext_vector_type(8)));

__device__ __forceinline__ unsigned short f2bf_rne(float f) {
    union { float f; uint32_t u; } c; c.f = f;
    uint32_t u = c.u;
    return (unsigned short)((u + 0x7fffu + ((u >> 16) & 1u)) >> 16);
}
__device__ __forceinline__ float bf2f(unsigned short h) {
    union { float f; uint32_t u; } c; c.u = ((uint32_t)h) << 16;
    return c.f;
}

// async global->LDS, 16B per lane; lds dest = uniform base + lane*16 (HW adds)
__device__ __forceinline__ void dma16(const void* g, void* l) {
    __builtin_amdgcn_global_load_lds(
        (const __attribute__((address_space(1))) void*)g,
        (__attribute__((address_space(3))) void*)l, 16, 0, 0);
}

#define MFMA32(A, B, C) __builtin_amdgcn_mfma_f32_32x32x16_bf16((A), (B), (C), 0, 0, 0)

// ---------------------------------------------------------------------------
// Prep: split embedding into bf16 hi/lo in the A-FRAGMENT-COALESCED layout:
//   ushort idx(code,c) = (code>>5)*8192 + (c>>4)*512 + (code&31)*16
//                        + ((c>>3)&1)*8 + (c&7)
// so a wave's per-kc fragment load (lane (m_,g) reads 16B) is one fully
// coalesced 1KB global_load_dwordx4 per instruction. Values identical to
// before (same f2bf_rne splits), only the address permutation changed.
// Also enorm (exact R1 reduction order), zero counts/losssum.
// ---------------------------------------------------------------------------
__global__ __launch_bounds__(256) void vq_prep(const float* __restrict__ emb,
                                               unsigned short* __restrict__ abt_h,
                                               unsigned short* __restrict__ abt_l,
                                               float* __restrict__ enorm,
                                               float* __restrict__ counts,
                                               float* __restrict__ losssum) {
    int tid = threadIdx.x;
    if (blockIdx.x == 0) {
        for (int i = tid; i < KCODE; i += 256) counts[i] = 0.0f;
        if (tid == 0) losssum[0] = 0.0f;
    }
    int w = tid >> 6, lane = tid & 63;
    int k = blockIdx.x * 4 + w;
    const float* row = emb + (size_t)k * CDIM;
    float s = 0.0f;
#pragma unroll
    for (int i = 0; i < 4; ++i) {
        float v = row[lane + 64 * i];
        s = fmaf(v, v, s);
    }
#pragma unroll
    for (int m = 32; m > 0; m >>= 1) s += __shfl_xor(s, m, 64);
    if (lane == 0) enorm[k] = s;

    float4 v4 = *(const float4*)(row + lane * 4);
    unsigned short h0 = f2bf_rne(v4.x), h1 = f2bf_rne(v4.y),
                   h2 = f2bf_rne(v4.z), h3 = f2bf_rne(v4.w);
    ushort4 hv = make_ushort4(h0, h1, h2, h3);
    ushort4 lv = make_ushort4(f2bf_rne(v4.x - bf2f(h0)), f2bf_rne(v4.y - bf2f(h1)),
                              f2bf_rne(v4.z - bf2f(h2)), f2bf_rne(v4.w - bf2f(h3)));
    // c = lane*4: kc = lane>>2, g = (lane>>1)&1, j = (lane&1)*4
    size_t dst = (size_t)(k >> 5) * 8192 + (lane >> 2) * 512 + (k & 31) * 16 +
                 ((lane >> 1) & 1) * 8 + (lane & 1) * 4;
    *(ushort4*)(abt_h + dst) = hv;
    *(ushort4*)(abt_l + dst) = lv;
}

// ---------------------------------------------------------------------------
// Main: 256 blocks x 512 threads (8 waves, 2/SIMD, 1 block/CU).
// ZERO main-loop barriers: A-fragments stream from global (L2-resident,
// coalesced 1KB loads, compiler vmcnt-pipelined); z tile lives in LDS as
// bf16 hi/lo planes zt[col][K] with XOR swizzle (^(col&7)<<4, bank-optimal
// for the wave ds_read_b128 pattern).
// Wave w: cq8 = w>>1 (256 codes = 8 blocks of 32), cv = w&1 (64 cols,
// 2 tiles). Per cs-pair iteration: acc[2cs][2t], 16 kc x {4 global A loads,
// 4 ds B reads, 12 MFMA}. Per-(code,col) 3-MFMA chain over kc=0..15 is
// bit-identical to R1-R4; epilogue formula identical; argmin lexicographic
// (d,code) (order-independent, R2-proven); merge ascending-code via LDS.
// Gather/loss tail = R1 verbatim (bitwise loss partials).
// ---------------------------------------------------------------------------
__global__ __launch_bounds__(512, 2) void vq_main(const float* __restrict__ z,
                                                  const float* __restrict__ emb,
                                                  const unsigned short* __restrict__ abt_h,
                                                  const unsigned short* __restrict__ abt_l,
                                                  const float* __restrict__ enorm,
                                                  float* __restrict__ counts,
                                                  float* __restrict__ losssum,
                                                  float* __restrict__ out) {
    // layout: zt_h@0 (64K) | zt_l@65536 (64K) | ens@131072 (4K) | zzs@135168
    //         (512) | pb_s@135680 (2K) | pb_i@137728 (2K) | bidxs@139776 (512)
    // gather slots reuse [0, 133120) (zt + dead ens head).
    __shared__ __align__(16) unsigned char lds[140288];
    float* ens_s = (float*)(lds + 131072);
    float* zzs   = (float*)(lds + 135168);
    float* pb_s  = (float*)(lds + 135680);
    int*   pb_i  = (int*)(lds + 137728);
    int*   bidxs = (int*)(lds + 139776);

    const int tid = threadIdx.x;
    const int w = tid >> 6;            // wave id 0..7
    const int lane = tid & 63;
    const int m_ = lane & 31;
    const int g = lane >> 5;
    const int bid = blockIdx.x;
    const int n0 = bid * 128;
    const int b = n0 >> 12;
    const int sp0 = n0 & 4095;
    const float* zb = z + (size_t)b * CDIM * SPAT + sp0;

    // ---- phase 1: convert z tile -> LDS bf16 planes; zz; enorm copy ----
    // converters: waves 0-5 (384 thr), 4096 (col,chunk) tasks, coalesced
    // across threads per j. zz: waves 6-7 (128 thr), exact sequential chain.
    if (tid < 384) {
#pragma unroll
        for (int it = 0; it < 11; ++it) {
            int task = tid + it * 384;
            if (task < 4096) {
                int col = task & 127, chunk = task >> 7;   // chunk 0..31
                ushort8 hv, lv;
#pragma unroll
                for (int j = 0; j < 8; ++j) {
                    float f = zb[(size_t)(chunk * 8 + j) * SPAT + col];
                    unsigned short hb = f2bf_rne(f);
                    hv[j] = hb;
                    lv[j] = f2bf_rne(f - bf2f(hb));
                }
                int baddr = (col * 512 + chunk * 16) ^ ((col & 7) << 4);
                *(ushort8*)(lds + baddr) = hv;
                *(ushort8*)(lds + 65536 + baddr) = lv;
            }
        }
    } else {
        int col = tid - 384;           // 0..127
        float s = 0.0f;
        for (int c = 0; c < CDIM; ++c) {
            float v = zb[(size_t)c * SPAT + col];
            s = fmaf(v, v, s);
        }
        zzs[col] = s;
    }
    for (int i = tid; i < KCODE; i += 512) ens_s[i] = enorm[i];
    __syncthreads();

    // ---- main loop: no barriers ----
    const int cq8 = w >> 1;            // code quarter (256 codes)
    const int cv = w & 1;              // col half (64 cols)
    const int aoff = m_ * 32 + g * 16; // per-lane A-frag byte offset
    const int col0 = cv * 64 + m_;
    const int col1 = col0 + 32;
    const int swz = (col0 & 7) << 4;   // col1 has same low-3 bits
    const int bo0 = col0 * 512 + g * 16;
    const int bo1 = col1 * 512 + g * 16;
    const float zzv0 = zzs[col0], zzv1 = zzs[col1];

    float bs0 = 3.4e38f, bs1 = 3.4e38f;
    int bi0 = 0, bi1 = 0;

    const floatx16 z16 = {0.0f, 0.0f, 0.0f, 0.0f, 0.0f, 0.0f, 0.0f, 0.0f,
                          0.0f, 0.0f, 0.0f, 0.0f, 0.0f, 0.0f, 0.0f, 0.0f};

    for (int cpi = 0; cpi < 4; ++cpi) {
        const int cp = (cpi + bid) & 3;          // per-block rotation
        const int blkA = cq8 * 8 + cp * 2;       // 32-code block
        const int blkB = blkA + 1;
        const char* pAh = (const char*)abt_h + ((size_t)blkA << 14) + aoff;
        const char* pAl = (const char*)abt_l + ((size_t)blkA << 14) + aoff;
        const char* pBh = (const char*)abt_h + ((size_t)blkB << 14) + aoff;
        const char* pBl = (const char*)abt_l + ((size_t)blkB << 14) + aoff;
        floatx16 a00 = z16, a01 = z16, a10 = z16, a11 = z16;
#pragma unroll
        for (int kc = 0; kc < 16; ++kc) {
            bf16x8 aeh0 = *(const bf16x8*)(pAh + kc * 1024);
            bf16x8 ael0 = *(const bf16x8*)(pAl + kc * 1024);
            bf16x8 aeh1 = *(const bf16x8*)(pBh + kc * 1024);
            bf16x8 ael1 = *(const bf16x8*)(pBl + kc * 1024);
            bf16x8 bh0 = *(const bf16x8*)(lds + ((bo0 + kc * 32) ^ swz));
            bf16x8 bl0 = *(const bf16x8*)(lds + 65536 + ((bo0 + kc * 32) ^ swz));
            bf16x8 bh1 = *(const bf16x8*)(lds + ((bo1 + kc * 32) ^ swz));
            bf16x8 bl1 = *(const bf16x8*)(lds + 65536 + ((bo1 + kc * 32) ^ swz));
            a00 = MFMA32(aeh0, bh0, a00); a00 = MFMA32(ael0, bh0, a00); a00 = MFMA32(aeh0, bl0, a00);
            a01 = MFMA32(aeh0, bh1, a01); a01 = MFMA32(ael0, bh1, a01); a01 = MFMA32(aeh0, bl1, a01);
            a10 = MFMA32(aeh1, bh0, a10); a10 = MFMA32(ael1, bh0, a10); a10 = MFMA32(aeh1, bl0, a10);
            a11 = MFMA32(aeh1, bh1, a11); a11 = MFMA32(ael1, bh1, a11); a11 = MFMA32(aeh1, bl1, a11);
        }
        // epilogue: order-independent lexicographic (d, code) argmin
#pragma unroll
        for (int reg = 0; reg < 16; ++reg) {
            int mm = (reg & 3) + 8 * (reg >> 2) + 4 * g;
            int code0 = blkA * 32 + mm, code1 = blkB * 32 + mm;
            float en0 = ens_s[code0], en1 = ens_s[code1];
            float d;
            d = (zzv0 + en0) - 2.0f * a00[reg];
            if (d < bs0 || (d == bs0 && code0 < bi0)) { bs0 = d; bi0 = code0; }
            d = (zzv1 + en0) - 2.0f * a01[reg];
            if (d < bs1 || (d == bs1 && code0 < bi1)) { bs1 = d; bi1 = code0; }
            d = (zzv0 + en1) - 2.0f * a10[reg];
            if (d < bs0 || (d == bs0 && code1 < bi0)) { bs0 = d; bi0 = code1; }
            d = (zzv1 + en1) - 2.0f * a11[reg];
            if (d < bs1 || (d == bs1 && code1 < bi1)) { bs1 = d; bi1 = code1; }
        }
    }

    // ---- merge g-halves (disjoint code subsets), tie -> low index ----
    {
        float s2 = __shfl_xor(bs0, 32, 64);
        int i2 = __shfl_xor(bi0, 32, 64);
        if (s2 < bs0 || (s2 == bs0 && i2 < bi0)) { bs0 = s2; bi0 = i2; }
        float s3 = __shfl_xor(bs1, 32, 64);
        int i3 = __shfl_xor(bi1, 32, 64);
        if (s3 < bs1 || (s3 == bs1 && i3 < bi1)) { bs1 = s3; bi1 = i3; }
    }
    if (lane < 32) {
        pb_s[cq8 * 128 + col0] = bs0; pb_i[cq8 * 128 + col0] = bi0;
        pb_s[cq8 * 128 + col1] = bs1; pb_i[cq8 * 128 + col1] = bi1;
    }
    __syncthreads();      // all waves done: pb complete, zt reads finished
    if (tid < 128) {
        float s = pb_s[tid];
        int ki = pb_i[tid];
#pragma unroll
        for (int q = 1; q < 4; ++q) {          // ascending code-quarters
            float s2 = pb_s[q * 128 + tid];
            int i2 = pb_i[q * 128 + tid];
            if (s2 < s || (s2 == s && i2 < ki)) { s = s2; ki = i2; }
        }
        bidxs[tid] = ki;
        out[IDX_OFF + n0 + tid] = (float)ki;
        atomicAdd(&counts[ki], 1.0f);
    }
    __syncthreads();

    // ---- DMA the 128 selected embedding rows into LDS (slots reuse zt) ----
    // slot(row) = (row&3)*32 + (row>>2); byte offset slot*1040 (16B aligned).
#pragma unroll
    for (int r = 0; r < 16; ++r) {
        int row = w * 16 + r;
        int k = bidxs[row];
        int slot = (row & 3) * 32 + (row >> 2);
        dma16((const char*)emb + ((size_t)k << 10) + (lane << 4),
              (char*)lds + (size_t)slot * 1040);
    }
    __syncthreads();

    // ---- gather z_q, STE output zp + (q - zp), loss ----
    // EXACT R1 256-thread mapping (bitwise loss); waves 4-7 retire.
    if (tid < 256) {
        float ls = 0.0f;
        float* outz = out + (size_t)b * CDIM * SPAT + sp0;
        const int col4 = tid & 31;         // this thread's 4 columns
        const int c_0 = tid >> 5;          // starting c, stride 8
        const float* e0 = (const float*)(lds + (size_t)(0 * 32 + col4) * 1040);
        const float* e1 = (const float*)(lds + (size_t)(1 * 32 + col4) * 1040);
        const float* e2 = (const float*)(lds + (size_t)(2 * 32 + col4) * 1040);
        const float* e3 = (const float*)(lds + (size_t)(3 * 32 + col4) * 1040);
        for (int c = c_0; c < CDIM; c += 8) {
            float4 zp = *(const float4*)(zb + (size_t)c * SPAT + col4 * 4);
            float d0 = e0[c] - zp.x, d1 = e1[c] - zp.y,
                  d2 = e2[c] - zp.z, d3 = e3[c] - zp.w;
            float4 o;
            o.x = zp.x + d0; o.y = zp.y + d1; o.z = zp.z + d2; o.w = zp.w + d3;
            ls = fmaf(d0, d0, ls); ls = fmaf(d1, d1, ls);
            ls = fmaf(d2, d2, ls); ls = fmaf(d3, d3, ls);
            *(float4*)(outz + (size_t)c * SPAT + col4 * 4) = o;
        }
#pragma unroll
        for (int m = 32; m > 0; m >>= 1) ls += __shfl_xor(ls, m, 64);
        if (lane == 0) atomicAdd(losssum, ls);
    }
}

// ---------------------------------------------------------------------------
// loss + perplexity
// ---------------------------------------------------------------------------
__global__ __launch_bounds__(256) void vq_finalize(const float* __restrict__ counts,
                                                   const float* __restrict__ losssum,
                                                   float* __restrict__ out) {
    __shared__ float red[256];
    int tid = threadIdx.x;
    float s = 0.0f;
    for (int k = tid; k < KCODE; k += 256) {
        float em = counts[k] * (1.0f / 32768.0f);
        s += em * logf(em + 1e-10f);
    }
    red[tid] = s;
    __syncthreads();
    for (int off = 128; off > 0; off >>= 1) {
        if (tid < off) red[tid] += red[tid + off];
        __syncthreads();
    }
    if (tid == 0) {
        float m = losssum[0] * (1.0f / 8388608.0f);
        out[LOSS_OFF] = m + 0.25f * m;
        out[PERP_OFF] = expf(-red[0]);
    }
}

extern "C" void kernel_launch(void* const* d_in, const int* in_sizes, int n_in,
                              void* d_out, int out_size, void* d_ws, size_t ws_size,
                              hipStream_t stream) {
    const float* z = (const float*)d_in[0];
    const float* emb = (const float*)d_in[1];
    float* out = (float*)d_out;
    // workspace: abt_h | abt_l | enorm | counts | losssum
    unsigned short* abt_h = (unsigned short*)d_ws;           // 1024*256 ushort
    unsigned short* abt_l = abt_h + (size_t)KCODE * CDIM;    // 1024*256 ushort
    float* enorm = (float*)(abt_l + (size_t)KCODE * CDIM);   // 1024 f
    float* counts = enorm + KCODE;                           // 1024 f
    float* losssum = counts + KCODE;                         // 1 f

    vq_prep<<<256, 256, 0, stream>>>(emb, abt_h, abt_l, enorm, counts, losssum);
    vq_main<<<256, 512, 0, stream>>>(z, emb, abt_h, abt_l, enorm,
                                     counts, losssum, out);
    vq_finalize<<<1, 256, 0, stream>>>(counts, losssum, out);
}